// Round 1
// baseline (191.679 us; speedup 1.0000x reference)
//
#include <hip/hip_runtime.h>
#include <math.h>

#define S_LEN 2048
#define DMODEL 1024
#define NHEAD 16
#define DHEAD 64
#define WIN 128
#define NQKV 1152  // DHEAD*(NHEAD+2)

using bf16x8 = __attribute__((ext_vector_type(8))) short;
using f32x4  = __attribute__((ext_vector_type(4))) float;

__device__ __forceinline__ unsigned short f2bf(float f) {
  union { float f; unsigned u; } v; v.f = f;
  unsigned u = v.u;
  u += 0x7FFFu + ((u >> 16) & 1u);   // RNE
  return (unsigned short)(u >> 16);
}
__device__ __forceinline__ float bf2f(unsigned short h) {
  union { unsigned u; float f; } v; v.u = ((unsigned)h) << 16;
  return v.f;
}

// ---------------------------------------------------------------- convert
__global__ __launch_bounds__(256)
void convert_kernel(const float4* __restrict__ x, const float4* __restrict__ wq,
                    const float4* __restrict__ wo,
                    ushort4* __restrict__ xhi, ushort4* __restrict__ xlo,
                    ushort4* __restrict__ whi, ushort4* __restrict__ wlo,
                    ushort4* __restrict__ wouth) {
  const int NX4 = (S_LEN * DMODEL) / 4;
  const int NW4 = (NQKV * DMODEL) / 4;
  const int NO4 = (DMODEL * DMODEL) / 4;
  const int i = blockIdx.x * 256 + threadIdx.x;
  if (i < NX4) {
    const float4 v = x[i];
    ushort4 h, l;
    h.x = f2bf(v.x); l.x = f2bf(v.x - bf2f(h.x));
    h.y = f2bf(v.y); l.y = f2bf(v.y - bf2f(h.y));
    h.z = f2bf(v.z); l.z = f2bf(v.z - bf2f(h.z));
    h.w = f2bf(v.w); l.w = f2bf(v.w - bf2f(h.w));
    xhi[i] = h; xlo[i] = l;
  } else if (i < NX4 + NW4) {
    const int j = i - NX4;
    const float4 v = wq[j];
    ushort4 h, l;
    h.x = f2bf(v.x); l.x = f2bf(v.x - bf2f(h.x));
    h.y = f2bf(v.y); l.y = f2bf(v.y - bf2f(h.y));
    h.z = f2bf(v.z); l.z = f2bf(v.z - bf2f(h.z));
    h.w = f2bf(v.w); l.w = f2bf(v.w - bf2f(h.w));
    whi[j] = h; wlo[j] = l;
  } else {
    const int j = i - NX4 - NW4;
    if (j < NO4) {
      const float4 v = wo[j];
      ushort4 h;
      h.x = f2bf(v.x); h.y = f2bf(v.y); h.z = f2bf(v.z); h.w = f2bf(v.w);
      wouth[j] = h;
    }
  }
}

// ---------------------------------------------------------------- GEMM: C[M][N] = A[M][K] * B[N][K]^T + bias[N]
// A,B bf16 (optionally hi+lo split), C fp32. BM=BN=64, BK=32.
template<bool SPLIT>
__global__ __launch_bounds__(256)
void gemm_bt(const ushort* __restrict__ Ahi, const ushort* __restrict__ Alo,
             const ushort* __restrict__ Bhi, const ushort* __restrict__ Blo,
             const float* __restrict__ bias, float* __restrict__ C,
             int M, int N, int K) {
  __shared__ __align__(16) ushort sAh[64 * 40];
  __shared__ __align__(16) ushort sBh[64 * 40];
  __shared__ __align__(16) ushort sAl[64 * 40];
  __shared__ __align__(16) ushort sBl[64 * 40];
  const int t = threadIdx.x;
  const int wave = t >> 6, lane = t & 63;
  const int quad = lane >> 4, l16 = lane & 15;
  const int wm = (wave >> 1) * 32, wn = (wave & 1) * 32;
  const int m0 = blockIdx.x * 64, n0 = blockIdx.y * 64;
  const int srow = t >> 2, sc8 = (t & 3) * 8;

  f32x4 acc[2][2] = {};

  const long aBase = (long)(m0 + srow) * K + sc8;
  const long bBase = (long)(n0 + srow) * K + sc8;

  for (int k0 = 0; k0 < K; k0 += 32) {
    __syncthreads();
    *(uint4*)(&sAh[srow * 40 + sc8]) = *(const uint4*)(Ahi + aBase + k0);
    *(uint4*)(&sBh[srow * 40 + sc8]) = *(const uint4*)(Bhi + bBase + k0);
    if (SPLIT) {
      *(uint4*)(&sAl[srow * 40 + sc8]) = *(const uint4*)(Alo + aBase + k0);
      *(uint4*)(&sBl[srow * 40 + sc8]) = *(const uint4*)(Blo + bBase + k0);
    }
    __syncthreads();
    bf16x8 ah[2], bh[2], al[2], bl[2];
#pragma unroll
    for (int i = 0; i < 2; ++i) {
      ah[i] = *(const bf16x8*)(&sAh[(wm + i * 16 + l16) * 40 + quad * 8]);
      bh[i] = *(const bf16x8*)(&sBh[(wn + i * 16 + l16) * 40 + quad * 8]);
      if (SPLIT) {
        al[i] = *(const bf16x8*)(&sAl[(wm + i * 16 + l16) * 40 + quad * 8]);
        bl[i] = *(const bf16x8*)(&sBl[(wn + i * 16 + l16) * 40 + quad * 8]);
      }
    }
#pragma unroll
    for (int i = 0; i < 2; ++i)
#pragma unroll
      for (int j = 0; j < 2; ++j) {
        acc[i][j] = __builtin_amdgcn_mfma_f32_16x16x32_bf16(ah[i], bh[j], acc[i][j], 0, 0, 0);
        if (SPLIT) {
          acc[i][j] = __builtin_amdgcn_mfma_f32_16x16x32_bf16(ah[i], bl[j], acc[i][j], 0, 0, 0);
          acc[i][j] = __builtin_amdgcn_mfma_f32_16x16x32_bf16(al[i], bh[j], acc[i][j], 0, 0, 0);
        }
      }
  }
#pragma unroll
  for (int i = 0; i < 2; ++i)
#pragma unroll
    for (int j = 0; j < 2; ++j) {
      const int col = n0 + wn + j * 16 + l16;
      const float b = bias[col];
#pragma unroll
      for (int r = 0; r < 4; ++r) {
        const int row = m0 + wm + i * 16 + quad * 4 + r;
        C[(long)row * N + col] = acc[i][j][r] + b;
      }
    }
}

// ---------------------------------------------------------------- attention (fp32 VALU), one block per query row i
__global__ __launch_bounds__(256)
void attn_kernel(const float* __restrict__ qkv, ushort* __restrict__ obuf) {
  __shared__ __align__(16) float  q_s[16 * 68];
  __shared__ __align__(16) float  k_s[128 * 68];
  __shared__ __align__(16) ushort v_s[128 * 64];
  __shared__ __align__(16) float  p_s[16 * 128];
  __shared__ float l_s[16];

  const int i = blockIdx.x;
  const int t = threadIdx.x;
  const int jlo = (i >= WIN - 1) ? (i - (WIN - 1)) : 0;
  const int nj = i - jlo + 1;  // 1..128 valid rows

  {  // stage q (fp32)
    const int h = t >> 4, d4 = (t & 15) * 4;
    *(float4*)(&q_s[h * 68 + d4]) =
        *(const float4*)(qkv + (long)i * NQKV + 2 * DHEAD + h * DHEAD + d4);
  }
#pragma unroll
  for (int rr = 0; rr < 8; ++rr) {  // stage K fp32, V bf16
    const int row = rr * 16 + (t >> 4);
    const int c4 = (t & 15) * 4;
    float4 kv = make_float4(0.f, 0.f, 0.f, 0.f);
    float4 vv = make_float4(0.f, 0.f, 0.f, 0.f);
    if (row < nj) {
      kv = *(const float4*)(qkv + (long)(jlo + row) * NQKV + c4);
      vv = *(const float4*)(qkv + (long)(jlo + row) * NQKV + DHEAD + c4);
    }
    *(float4*)(&k_s[row * 68 + c4]) = kv;
    ushort4 vb;
    vb.x = f2bf(vv.x); vb.y = f2bf(vv.y); vb.z = f2bf(vv.z); vb.w = f2bf(vv.w);
    *(ushort4*)(&v_s[row * 64 + c4]) = vb;
  }
  __syncthreads();

  {  // scores: thread handles heads {h0,h0+8}, j = jg+32v
    const int h0 = t >> 5;
    const int jg = t & 31;
    float a0[4] = {0, 0, 0, 0}, a1[4] = {0, 0, 0, 0};
#pragma unroll
    for (int c = 0; c < 16; ++c) {
      const float4 qa = *(const float4*)(&q_s[h0 * 68 + c * 4]);
      const float4 qb = *(const float4*)(&q_s[(h0 + 8) * 68 + c * 4]);
#pragma unroll
      for (int v = 0; v < 4; ++v) {
        const float4 kk = *(const float4*)(&k_s[(jg + 32 * v) * 68 + c * 4]);
        a0[v] += qa.x * kk.x + qa.y * kk.y + qa.z * kk.z + qa.w * kk.w;
        a1[v] += qb.x * kk.x + qb.y * kk.y + qb.z * kk.z + qb.w * kk.w;
      }
    }
#pragma unroll
    for (int v = 0; v < 4; ++v) {
      const int j = jg + 32 * v;
      const bool valid = j < nj;
      p_s[h0 * 128 + j]       = valid ? 8.0f * a0[v] : -1e30f;
      p_s[(h0 + 8) * 128 + j] = valid ? 8.0f * a1[v] : -1e30f;
    }
  }
  __syncthreads();

  {  // softmax per head: 16-lane groups
    const int h = t >> 4, g = t & 15;
    float vals[8];
    float m = -1e30f;
#pragma unroll
    for (int r = 0; r < 8; ++r) {
      vals[r] = p_s[h * 128 + g + 16 * r];
      m = fmaxf(m, vals[r]);
    }
#pragma unroll
    for (int off = 1; off < 16; off <<= 1) m = fmaxf(m, __shfl_xor(m, off));
    float lsum = 0.0f;
#pragma unroll
    for (int r = 0; r < 8; ++r) {
      const float e = __expf(vals[r] - m);
      p_s[h * 128 + g + 16 * r] = e;
      lsum += e;
    }
#pragma unroll
    for (int off = 1; off < 16; off <<= 1) lsum += __shfl_xor(lsum, off);
    if (g == 0) l_s[h] = lsum;
  }
  __syncthreads();

  {  // PV: thread = (h, 4-wide d chunk)
    const int h = t >> 4, dc = t & 15;
    float o0 = 0.f, o1 = 0.f, o2 = 0.f, o3 = 0.f;
#pragma unroll 8
    for (int j = 0; j < 128; ++j) {
      const float pj = p_s[h * 128 + j];
      const ushort4 vb = *(const ushort4*)(&v_s[j * 64 + dc * 4]);
      o0 += pj * bf2f(vb.x);
      o1 += pj * bf2f(vb.y);
      o2 += pj * bf2f(vb.z);
      o3 += pj * bf2f(vb.w);
    }
    const float inv = 1.0f / l_s[h];
    ushort4 ob;
    ob.x = f2bf(o0 * inv); ob.y = f2bf(o1 * inv);
    ob.z = f2bf(o2 * inv); ob.w = f2bf(o3 * inv);
    *(ushort4*)(&obuf[(long)i * DMODEL + h * DHEAD + dc * 4]) = ob;
  }
}

// ---------------------------------------------------------------- launch
extern "C" void kernel_launch(void* const* d_in, const int* in_sizes, int n_in,
                              void* d_out, int out_size, void* d_ws, size_t ws_size,
                              hipStream_t stream) {
  const float* x    = (const float*)d_in[0];
  const float* Wqkv = (const float*)d_in[1];
  const float* bqkv = (const float*)d_in[2];
  const float* Wout = (const float*)d_in[3];
  const float* bout = (const float*)d_in[4];
  float* out = (float*)d_out;

  char* w = (char*)d_ws;
  // workspace layout (all 16B aligned)
  ushort* xhi   = (ushort*)(w + 0);          //  4,194,304 B
  ushort* xlo   = (ushort*)(w + 4194304);    //  4,194,304 B
  ushort* whi   = (ushort*)(w + 8388608);    //  2,359,296 B
  ushort* wlo   = (ushort*)(w + 10747904);   //  2,359,296 B
  ushort* wouth = (ushort*)(w + 13107200);   //  2,097,152 B
  float*  qkv   = (float*)(w + 15204352);    //  9,437,184 B
  ushort* obuf  = (ushort*)(w + 24641536);   //  4,194,304 B  (total ~27.5 MB)

  convert_kernel<<<4224, 256, 0, stream>>>(
      (const float4*)x, (const float4*)Wqkv, (const float4*)Wout,
      (ushort4*)xhi, (ushort4*)xlo, (ushort4*)whi, (ushort4*)wlo, (ushort4*)wouth);

  dim3 g1(S_LEN / 64, NQKV / 64);  // 32 x 18
  gemm_bt<true><<<g1, 256, 0, stream>>>(xhi, xlo, whi, wlo, bqkv, qkv,
                                        S_LEN, NQKV, DMODEL);

  attn_kernel<<<S_LEN, 256, 0, stream>>>(qkv, obuf);

  dim3 g2(S_LEN / 64, DMODEL / 64);  // 32 x 16
  gemm_bt<false><<<g2, 256, 0, stream>>>(obuf, obuf, wouth, wouth, bout, out,
                                         S_LEN, DMODEL, DMODEL);
}

// Round 2
// 140.198 us; speedup vs baseline: 1.3672x; 1.3672x over previous
//
#include <hip/hip_runtime.h>
#include <math.h>

#define S_LEN 2048
#define DMODEL 1024
#define NHEAD 16
#define DHEAD 64
#define WIN 128
#define NQKV 1152  // DHEAD*(NHEAD+2)

using bf16x8 = __attribute__((ext_vector_type(8))) short;
using f32x4  = __attribute__((ext_vector_type(4))) float;

__device__ __forceinline__ unsigned short f2bf(float f) {
  union { float f; unsigned u; } v; v.f = f;
  unsigned u = v.u;
  u += 0x7FFFu + ((u >> 16) & 1u);   // RNE
  return (unsigned short)(u >> 16);
}
__device__ __forceinline__ float bf2f(unsigned short h) {
  union { unsigned u; float f; } v; v.u = ((unsigned)h) << 16;
  return v.f;
}

// ---------------------------------------------------------------- convert
__global__ __launch_bounds__(256)
void convert_kernel(const float4* __restrict__ x, const float4* __restrict__ wq,
                    const float4* __restrict__ wo,
                    ushort4* __restrict__ xhi, ushort4* __restrict__ xlo,
                    ushort4* __restrict__ whi, ushort4* __restrict__ wlo,
                    ushort4* __restrict__ wouth) {
  const int NX4 = (S_LEN * DMODEL) / 4;
  const int NW4 = (NQKV * DMODEL) / 4;
  const int NO4 = (DMODEL * DMODEL) / 4;
  const int i = blockIdx.x * 256 + threadIdx.x;
  if (i < NX4) {
    const float4 v = x[i];
    ushort4 h, l;
    h.x = f2bf(v.x); l.x = f2bf(v.x - bf2f(h.x));
    h.y = f2bf(v.y); l.y = f2bf(v.y - bf2f(h.y));
    h.z = f2bf(v.z); l.z = f2bf(v.z - bf2f(h.z));
    h.w = f2bf(v.w); l.w = f2bf(v.w - bf2f(h.w));
    xhi[i] = h; xlo[i] = l;
  } else if (i < NX4 + NW4) {
    const int j = i - NX4;
    const float4 v = wq[j];
    ushort4 h, l;
    h.x = f2bf(v.x); l.x = f2bf(v.x - bf2f(h.x));
    h.y = f2bf(v.y); l.y = f2bf(v.y - bf2f(h.y));
    h.z = f2bf(v.z); l.z = f2bf(v.z - bf2f(h.z));
    h.w = f2bf(v.w); l.w = f2bf(v.w - bf2f(h.w));
    whi[j] = h; wlo[j] = l;
  } else {
    const int j = i - NX4 - NW4;
    if (j < NO4) {
      const float4 v = wo[j];
      ushort4 h;
      h.x = f2bf(v.x); h.y = f2bf(v.y); h.z = f2bf(v.z); h.w = f2bf(v.w);
      wouth[j] = h;
    }
  }
}

// ---------------------------------------------------------------- GEMM: C[M][N] = A[M][K] * B[N][K]^T + bias[N]
template<bool SPLIT>
__global__ __launch_bounds__(256)
void gemm_bt(const ushort* __restrict__ Ahi, const ushort* __restrict__ Alo,
             const ushort* __restrict__ Bhi, const ushort* __restrict__ Blo,
             const float* __restrict__ bias, float* __restrict__ C,
             int M, int N, int K) {
  __shared__ __align__(16) ushort sAh[64 * 40];
  __shared__ __align__(16) ushort sBh[64 * 40];
  __shared__ __align__(16) ushort sAl[64 * 40];
  __shared__ __align__(16) ushort sBl[64 * 40];
  const int t = threadIdx.x;
  const int wave = t >> 6, lane = t & 63;
  const int quad = lane >> 4, l16 = lane & 15;
  const int wm = (wave >> 1) * 32, wn = (wave & 1) * 32;
  const int m0 = blockIdx.x * 64, n0 = blockIdx.y * 64;
  const int srow = t >> 2, sc8 = (t & 3) * 8;

  f32x4 acc[2][2] = {};

  const long aBase = (long)(m0 + srow) * K + sc8;
  const long bBase = (long)(n0 + srow) * K + sc8;

  for (int k0 = 0; k0 < K; k0 += 32) {
    __syncthreads();
    *(uint4*)(&sAh[srow * 40 + sc8]) = *(const uint4*)(Ahi + aBase + k0);
    *(uint4*)(&sBh[srow * 40 + sc8]) = *(const uint4*)(Bhi + bBase + k0);
    if (SPLIT) {
      *(uint4*)(&sAl[srow * 40 + sc8]) = *(const uint4*)(Alo + aBase + k0);
      *(uint4*)(&sBl[srow * 40 + sc8]) = *(const uint4*)(Blo + bBase + k0);
    }
    __syncthreads();
    bf16x8 ah[2], bh[2], al[2], bl[2];
#pragma unroll
    for (int i = 0; i < 2; ++i) {
      ah[i] = *(const bf16x8*)(&sAh[(wm + i * 16 + l16) * 40 + quad * 8]);
      bh[i] = *(const bf16x8*)(&sBh[(wn + i * 16 + l16) * 40 + quad * 8]);
      if (SPLIT) {
        al[i] = *(const bf16x8*)(&sAl[(wm + i * 16 + l16) * 40 + quad * 8]);
        bl[i] = *(const bf16x8*)(&sBl[(wn + i * 16 + l16) * 40 + quad * 8]);
      }
    }
#pragma unroll
    for (int i = 0; i < 2; ++i)
#pragma unroll
      for (int j = 0; j < 2; ++j) {
        acc[i][j] = __builtin_amdgcn_mfma_f32_16x16x32_bf16(ah[i], bh[j], acc[i][j], 0, 0, 0);
        if (SPLIT) {
          acc[i][j] = __builtin_amdgcn_mfma_f32_16x16x32_bf16(ah[i], bl[j], acc[i][j], 0, 0, 0);
          acc[i][j] = __builtin_amdgcn_mfma_f32_16x16x32_bf16(al[i], bh[j], acc[i][j], 0, 0, 0);
        }
      }
  }
#pragma unroll
  for (int i = 0; i < 2; ++i)
#pragma unroll
    for (int j = 0; j < 2; ++j) {
      const int col = n0 + wn + j * 16 + l16;
      const float b = bias[col];
#pragma unroll
      for (int r = 0; r < 4; ++r) {
        const int row = m0 + wm + i * 16 + quad * 4 + r;
        C[(long)row * N + col] = acc[i][j][r] + b;
      }
    }
}

// ---------------------------------------------------------------- MFMA flash attention
// Block: 8 queries x 16 heads = 128 M-rows (m = q_local*16 + head).
// Keys padded to 144 (9 N-tiles) for QK^T; PV runs 5 K-steps over 160 (P cols 144..159 zeroed).
// LDS: region [0, 43008B): Kh[144][72] + Kl[144][72] (41472B), later aliased by P[128][168] bf16.
//      region [43008, 64512B): Vt[64][168] bf16 (V transposed: Vt[d][key]).
#define QT 8
#define KSTRIDE 72
#define PSTRIDE 168

__global__ __launch_bounds__(256)
void attn_mfma_kernel(const float* __restrict__ qkv, ushort* __restrict__ obuf) {
  __shared__ __align__(16) ushort lds[32256];  // 64,512 B
  ushort* Kh = lds;                    // [144][72]
  ushort* Kl = lds + 144 * KSTRIDE;    // [144][72]
  ushort* P  = lds;                    // [128][168], aliases K after QK^T
  ushort* Vt = lds + 21504;            // [64][168]

  const int t = threadIdx.x;
  const int i0 = blockIdx.x * QT;
  const int jlo = (i0 >= WIN - 1) ? (i0 - (WIN - 1)) : 0;
  const int nj = i0 + QT - jlo;  // valid keys: jlo .. jlo+nj-1 (= i0+7)

  const int wave = t >> 6, lane = t & 63;
  const int quad = lane >> 4, l16 = lane & 15;

  // ---- stage K (hi/lo) and V (transposed bf16) into LDS
  {
    const int dc = (t & 15) * 4;
    const int jr = t >> 4;
#pragma unroll
    for (int j0 = 0; j0 < 144; j0 += 16) {
      const int j = j0 + jr;
      if (j < nj) {
        const float4 kv = *(const float4*)(qkv + (size_t)(jlo + j) * NQKV + dc);
        ushort4 h, l;
        h.x = f2bf(kv.x); l.x = f2bf(kv.x - bf2f(h.x));
        h.y = f2bf(kv.y); l.y = f2bf(kv.y - bf2f(h.y));
        h.z = f2bf(kv.z); l.z = f2bf(kv.z - bf2f(h.z));
        h.w = f2bf(kv.w); l.w = f2bf(kv.w - bf2f(h.w));
        *(ushort4*)(&Kh[j * KSTRIDE + dc]) = h;
        *(ushort4*)(&Kl[j * KSTRIDE + dc]) = l;
      }
    }
#pragma unroll
    for (int j0 = 0; j0 < 160; j0 += 16) {
      const int j = j0 + jr;
      float4 vv = make_float4(0.f, 0.f, 0.f, 0.f);
      if (j < nj) vv = *(const float4*)(qkv + (size_t)(jlo + j) * NQKV + DHEAD + dc);
      Vt[(dc + 0) * PSTRIDE + j] = f2bf(vv.x);
      Vt[(dc + 1) * PSTRIDE + j] = f2bf(vv.y);
      Vt[(dc + 2) * PSTRIDE + j] = f2bf(vv.z);
      Vt[(dc + 3) * PSTRIDE + j] = f2bf(vv.w);
    }
  }

  // ---- Q fragments in registers: wave handles queries i0+2*wave+{0,1}; lane row = head = l16
  bf16x8 qh[2][2], ql[2][2];
#pragma unroll
  for (int tt = 0; tt < 2; ++tt) {
    const int qrow = i0 + wave * 2 + tt;
    const float* qp = qkv + (size_t)qrow * NQKV + 2 * DHEAD + l16 * DHEAD;
#pragma unroll
    for (int kst = 0; kst < 2; ++kst) {
      const float4 a = *(const float4*)(qp + kst * 32 + quad * 8);
      const float4 b = *(const float4*)(qp + kst * 32 + quad * 8 + 4);
      const float f[8] = {a.x, a.y, a.z, a.w, b.x, b.y, b.z, b.w};
#pragma unroll
      for (int e = 0; e < 8; ++e) {
        const float s = f[e] * 8.0f;  // fold sqrt(D) into Q
        const unsigned short h = f2bf(s);
        qh[tt][kst][e] = (short)h;
        ql[tt][kst][e] = (short)f2bf(s - bf2f(h));
      }
    }
  }

  __syncthreads();

  // ---- QK^T: acc[tt][nt] covers rows=heads (quad*4+r), cols=keys (nt*16+l16)
  f32x4 acc[2][9] = {};
#pragma unroll
  for (int nt = 0; nt < 9; ++nt) {
#pragma unroll
    for (int kst = 0; kst < 2; ++kst) {
      const int off = (nt * 16 + l16) * KSTRIDE + kst * 32 + quad * 8;
      const bf16x8 bh = *(const bf16x8*)(&Kh[off]);
      const bf16x8 bl = *(const bf16x8*)(&Kl[off]);
#pragma unroll
      for (int tt = 0; tt < 2; ++tt) {
        acc[tt][nt] = __builtin_amdgcn_mfma_f32_16x16x32_bf16(qh[tt][kst], bh, acc[tt][nt], 0, 0, 0);
        acc[tt][nt] = __builtin_amdgcn_mfma_f32_16x16x32_bf16(ql[tt][kst], bh, acc[tt][nt], 0, 0, 0);
        acc[tt][nt] = __builtin_amdgcn_mfma_f32_16x16x32_bf16(qh[tt][kst], bl, acc[tt][nt], 0, 0, 0);
      }
    }
  }

  __syncthreads();  // all waves done reading K; K region now dead -> P may overwrite

  // ---- mask + softmax (registers/shfl), write P (bf16) to LDS
  float inv_l[2][4];
#pragma unroll
  for (int tt = 0; tt < 2; ++tt) {
    const int qg = i0 + wave * 2 + tt;
#pragma unroll
    for (int nt = 0; nt < 9; ++nt) {
      const int jg = jlo + nt * 16 + l16;
      const bool valid = (jg <= qg) && (jg >= qg - (WIN - 1));
#pragma unroll
      for (int r = 0; r < 4; ++r)
        if (!valid) acc[tt][nt][r] = -1e30f;
    }
#pragma unroll
    for (int r = 0; r < 4; ++r) {
      float m = acc[tt][0][r];
#pragma unroll
      for (int nt = 1; nt < 9; ++nt) m = fmaxf(m, acc[tt][nt][r]);
#pragma unroll
      for (int off = 1; off < 16; off <<= 1) m = fmaxf(m, __shfl_xor(m, off));
      float s = 0.f;
#pragma unroll
      for (int nt = 0; nt < 9; ++nt) {
        const float e = __expf(acc[tt][nt][r] - m);
        acc[tt][nt][r] = e;
        s += e;
      }
#pragma unroll
      for (int off = 1; off < 16; off <<= 1) s += __shfl_xor(s, off);
      inv_l[tt][r] = 1.0f / s;
    }
    const int mrow0 = (wave * 2 + tt) * 16 + quad * 4;
#pragma unroll
    for (int r = 0; r < 4; ++r)
#pragma unroll
      for (int nt = 0; nt < 9; ++nt)
        P[(mrow0 + r) * PSTRIDE + nt * 16 + l16] = f2bf(acc[tt][nt][r]);
  }
  // zero P cols 144..159 (PV 5th K-step padding)
  {
    const int row = t >> 1, ch = t & 1;
    *(uint4*)(&P[row * PSTRIDE + 144 + ch * 8]) = make_uint4(0u, 0u, 0u, 0u);
  }
  __syncthreads();

  // ---- PV: o[tt][nd] rows=heads (quad*4+r), cols=d (nd*16+l16)
  f32x4 o[2][4] = {};
#pragma unroll
  for (int kst = 0; kst < 5; ++kst) {
    const bf16x8 a0 = *(const bf16x8*)(&P[((wave * 2 + 0) * 16 + l16) * PSTRIDE + kst * 32 + quad * 8]);
    const bf16x8 a1 = *(const bf16x8*)(&P[((wave * 2 + 1) * 16 + l16) * PSTRIDE + kst * 32 + quad * 8]);
#pragma unroll
    for (int nd = 0; nd < 4; ++nd) {
      const bf16x8 b = *(const bf16x8*)(&Vt[(nd * 16 + l16) * PSTRIDE + kst * 32 + quad * 8]);
      o[0][nd] = __builtin_amdgcn_mfma_f32_16x16x32_bf16(a0, b, o[0][nd], 0, 0, 0);
      o[1][nd] = __builtin_amdgcn_mfma_f32_16x16x32_bf16(a1, b, o[1][nd], 0, 0, 0);
    }
  }

  // ---- epilogue: normalize, write obuf[i][head*64+d] bf16
#pragma unroll
  for (int tt = 0; tt < 2; ++tt) {
    const int orow = i0 + wave * 2 + tt;
#pragma unroll
    for (int nd = 0; nd < 4; ++nd)
#pragma unroll
      for (int r = 0; r < 4; ++r) {
        const int head = quad * 4 + r;
        const int col = head * DHEAD + nd * 16 + l16;
        obuf[(size_t)orow * DMODEL + col] = f2bf(o[tt][nd][r] * inv_l[tt][r]);
      }
  }
}

// ---------------------------------------------------------------- launch
extern "C" void kernel_launch(void* const* d_in, const int* in_sizes, int n_in,
                              void* d_out, int out_size, void* d_ws, size_t ws_size,
                              hipStream_t stream) {
  const float* x    = (const float*)d_in[0];
  const float* Wqkv = (const float*)d_in[1];
  const float* bqkv = (const float*)d_in[2];
  const float* Wout = (const float*)d_in[3];
  const float* bout = (const float*)d_in[4];
  float* out = (float*)d_out;

  char* w = (char*)d_ws;
  ushort* xhi   = (ushort*)(w + 0);
  ushort* xlo   = (ushort*)(w + 4194304);
  ushort* whi   = (ushort*)(w + 8388608);
  ushort* wlo   = (ushort*)(w + 10747904);
  ushort* wouth = (ushort*)(w + 13107200);
  float*  qkv   = (float*)(w + 15204352);
  ushort* obuf  = (ushort*)(w + 24641536);

  convert_kernel<<<4224, 256, 0, stream>>>(
      (const float4*)x, (const float4*)Wqkv, (const float4*)Wout,
      (ushort4*)xhi, (ushort4*)xlo, (ushort4*)whi, (ushort4*)wlo, (ushort4*)wouth);

  dim3 g1(S_LEN / 64, NQKV / 64);
  gemm_bt<true><<<g1, 256, 0, stream>>>(xhi, xlo, whi, wlo, bqkv, qkv,
                                        S_LEN, NQKV, DMODEL);

  attn_mfma_kernel<<<S_LEN / QT, 256, 0, stream>>>(qkv, obuf);

  dim3 g2(S_LEN / 64, DMODEL / 64);
  gemm_bt<false><<<g2, 256, 0, stream>>>(obuf, obuf, wouth, wouth, bout, out,
                                         S_LEN, DMODEL, DMODEL);
}

// Round 3
// 134.003 us; speedup vs baseline: 1.4304x; 1.0462x over previous
//
#include <hip/hip_runtime.h>
#include <math.h>

#define S_LEN 2048
#define DMODEL 1024
#define NHEAD 16
#define DHEAD 64
#define WIN 128
#define NQKV 1152

typedef _Float16 f16x8 __attribute__((ext_vector_type(8)));
typedef float f32x4 __attribute__((ext_vector_type(4)));

__device__ __forceinline__ ushort f2h(float f) {
  union { _Float16 h; ushort u; } v; v.h = (_Float16)f; return v.u;
}

typedef __attribute__((address_space(1))) const unsigned GU;
typedef __attribute__((address_space(3))) unsigned LU;
__device__ __forceinline__ void async16(const ushort* g, ushort* l) {
  __builtin_amdgcn_global_load_lds((GU*)g, (LU*)l, 16, 0, 0);
}

// ---------------------------------------------------------------- convert fp32 -> f16
__global__ __launch_bounds__(256)
void convert_kernel(const float4* __restrict__ x, const float4* __restrict__ wq,
                    const float4* __restrict__ wo,
                    ushort4* __restrict__ x16, ushort4* __restrict__ w16,
                    ushort4* __restrict__ wo16) {
  const int NX4 = (S_LEN * DMODEL) / 4;       // 524288
  const int NW4 = (NQKV * DMODEL) / 4;        // 294912
  const int NO4 = (DMODEL * DMODEL) / 4;      // 262144
  const int i = blockIdx.x * 256 + threadIdx.x;
  if (i < NX4) {
    const float4 v = x[i];
    ushort4 h; h.x = f2h(v.x); h.y = f2h(v.y); h.z = f2h(v.z); h.w = f2h(v.w);
    x16[i] = h;
  } else if (i < NX4 + NW4) {
    const int j = i - NX4;
    const float s = ((j >> 8) >= 2 * DHEAD) ? 8.0f : 1.0f;  // fold sqrt(D) into q-rows
    const float4 v = wq[j];
    ushort4 h; h.x = f2h(v.x * s); h.y = f2h(v.y * s); h.z = f2h(v.z * s); h.w = f2h(v.w * s);
    w16[j] = h;
  } else {
    const int j = i - NX4 - NW4;
    if (j < NO4) {
      const float4 v = wo[j];
      ushort4 h; h.x = f2h(v.x); h.y = f2h(v.y); h.z = f2h(v.z); h.w = f2h(v.w);
      wo16[j] = h;
    }
  }
}

// ---------------------------------------------------------------- 128x128 f16 GEMM (m97 structure)
// C[M][N] = A[M][K] * B[N][K]^T + bias. MODE 0: fp32 out. MODE 1: qkv epilogue ->
// k16[S][64] f16, vT[64][S] f16 (transposed!), q16[S][1024] f16 (bias x8 on q cols).
template<int MODE>
__global__ __launch_bounds__(256)
void gemm128(const ushort* __restrict__ A, const ushort* __restrict__ B,
             const float* __restrict__ bias, float* __restrict__ Cout,
             ushort* __restrict__ k16, ushort* __restrict__ vT, ushort* __restrict__ q16,
             int M, int N, int K) {
  __shared__ __align__(16) ushort sA[128 * 32];
  __shared__ __align__(16) ushort sB[128 * 32];
  const int t = threadIdx.x;
  const int w = t >> 6, lane = t & 63;
  const int quad = lane >> 4, l16 = lane & 15;
  const int wm = (w >> 1) * 64, wn = (w & 1) * 64;
  const int m0 = blockIdx.x * 128, n0 = blockIdx.y * 128;
  const int srow = lane >> 2, sc = (lane & 3) * 8;

  f32x4 acc[4][4] = {};
  const size_t aBase = (size_t)(m0 + 32 * w + srow) * K + sc;
  const size_t bBase = (size_t)(n0 + 32 * w + srow) * K + sc;
  ushort* ldsA0 = &sA[(32 * w) * 32];
  ushort* ldsA1 = &sA[(32 * w + 16) * 32];
  ushort* ldsB0 = &sB[(32 * w) * 32];
  ushort* ldsB1 = &sB[(32 * w + 16) * 32];

  for (int k0 = 0; k0 < K; k0 += 32) {
    __syncthreads();
    async16(A + aBase + k0, ldsA0);
    async16(A + aBase + (size_t)16 * K + k0, ldsA1);
    async16(B + bBase + k0, ldsB0);
    async16(B + bBase + (size_t)16 * K + k0, ldsB1);
    __syncthreads();
    f16x8 af[4], bf[4];
#pragma unroll
    for (int i = 0; i < 4; ++i)
      af[i] = *(const f16x8*)(&sA[(wm + 16 * i + l16) * 32 + quad * 8]);
#pragma unroll
    for (int j = 0; j < 4; ++j)
      bf[j] = *(const f16x8*)(&sB[(wn + 16 * j + l16) * 32 + quad * 8]);
#pragma unroll
    for (int i = 0; i < 4; ++i)
#pragma unroll
      for (int j = 0; j < 4; ++j)
        acc[i][j] = __builtin_amdgcn_mfma_f32_16x16x32_f16(af[i], bf[j], acc[i][j], 0, 0, 0);
  }

#pragma unroll
  for (int i = 0; i < 4; ++i)
#pragma unroll
    for (int j = 0; j < 4; ++j) {
      const int cb = n0 + wn + 16 * j;      // lane-uniform column base
      const int col = cb + l16;
      if (MODE == 0) {
        const float b = bias[col];
#pragma unroll
        for (int r = 0; r < 4; ++r) {
          const int row = m0 + wm + 16 * i + quad * 4 + r;
          Cout[(size_t)row * N + col] = acc[i][j][r] + b;
        }
      } else {
        const float bscale = (cb >= 2 * DHEAD) ? 8.0f : 1.0f;
        const float b = bias[col] * bscale;
#pragma unroll
        for (int r = 0; r < 4; ++r) {
          const int row = m0 + wm + 16 * i + quad * 4 + r;
          const ushort h = f2h(acc[i][j][r] + b);
          if (cb >= 2 * DHEAD) {
            q16[(size_t)row * DMODEL + (col - 2 * DHEAD)] = h;
          } else if (cb < DHEAD) {
            k16[(size_t)row * DHEAD + col] = h;
          } else {
            vT[(size_t)(col - DHEAD) * S_LEN + row] = h;
          }
        }
      }
    }
}

// ---------------------------------------------------------------- MFMA flash attention (f16)
// Block = 8 queries x 16 heads. Key window [jbase, jbase+192), jbase = (i0-127)&~7 (clamped 0).
// LDS: Ksw[192][64] f16 (chunk-swizzled, via global_load_lds), aliased after QK^T by P[128][208];
//      Vt[64][208] f16 staged from vT buffer. All masking in softmax (invalid -> P=0).
#define QT 8
#define PSTR 208

__global__ __launch_bounds__(256)
void attn_kernel(const ushort* __restrict__ k16, const ushort* __restrict__ vT,
                 const ushort* __restrict__ q16, ushort* __restrict__ obuf) {
  __shared__ __align__(16) ushort lds[128 * PSTR + 64 * PSTR];  // 79,872 B
  ushort* Ksw = lds;                  // [192][64] = 24,576 B (inside P region)
  ushort* P   = lds;                  // [128][208] = 53,248 B
  ushort* Vt  = lds + 128 * PSTR;     // [64][208]  = 26,624 B

  const int t = threadIdx.x;
  const int i0 = blockIdx.x * QT;
  const int jbase = (i0 >= WIN - 1) ? ((i0 - (WIN - 1)) & ~7) : 0;
  const int w = t >> 6, lane = t & 63;
  const int quad = lane >> 4, l16 = lane & 15;

  // ---- stage K: 24 async 1KB instrs, XOR chunk swizzle (chunk c of row r at pos c^(r&7))
#pragma unroll
  for (int i = 0; i < 6; ++i) {
    const int n = 6 * w + i;                 // 0..23, 8 rows each
    const int r = 8 * n + (lane >> 3);
    const int cs = (lane & 7) ^ (r & 7);
    async16(k16 + (size_t)(jbase + r) * DHEAD + cs * 8, &Ksw[n * 512]);
  }
  // ---- stage Vt[64][192] from vT (16B aligned since jbase%8==0)
  {
    const int d = t >> 2, p = t & 3;
#pragma unroll
    for (int it = 0; it < 6; ++it) {
      const int c = p + 4 * it;              // 0..23
      const uint4 raw = *(const uint4*)(vT + (size_t)d * S_LEN + jbase + c * 8);
      *(uint4*)(&Vt[d * PSTR + c * 8]) = raw;
    }
  }
  // ---- Q fragments: wave handles queries i0+2w+{0,1}; lane m-row = head = l16
  f16x8 qf[2][2];
#pragma unroll
  for (int tt = 0; tt < 2; ++tt) {
    const size_t qbase = (size_t)(i0 + 2 * w + tt) * DMODEL + l16 * DHEAD;
#pragma unroll
    for (int kst = 0; kst < 2; ++kst)
      qf[tt][kst] = *(const f16x8*)(q16 + qbase + kst * 32 + quad * 8);
  }
  __syncthreads();

  // ---- QK^T: acc[tt][nt], rows=heads (quad*4+r), cols=keys (nt*16+l16)
  f32x4 acc[2][12] = {};
#pragma unroll
  for (int nt = 0; nt < 12; ++nt) {
#pragma unroll
    for (int kst = 0; kst < 2; ++kst) {
      const int cp = ((kst << 2) | quad) ^ (l16 & 7);
      const f16x8 bf = *(const f16x8*)(&Ksw[(nt * 16 + l16) * 64 + cp * 8]);
      acc[0][nt] = __builtin_amdgcn_mfma_f32_16x16x32_f16(qf[0][kst], bf, acc[0][nt], 0, 0, 0);
      acc[1][nt] = __builtin_amdgcn_mfma_f32_16x16x32_f16(qf[1][kst], bf, acc[1][nt], 0, 0, 0);
    }
  }
  __syncthreads();  // K region dead; Vt stores drained

  // ---- mask + softmax (regs/shfl over 16 lanes), P -> LDS f16
  float inv_l[2][4];
#pragma unroll
  for (int tt = 0; tt < 2; ++tt) {
    const int qg = i0 + 2 * w + tt;
#pragma unroll
    for (int nt = 0; nt < 12; ++nt) {
      const int jg = jbase + nt * 16 + l16;
      const bool valid = (jg <= qg) && (jg > qg - WIN);
#pragma unroll
      for (int r = 0; r < 4; ++r)
        if (!valid) acc[tt][nt][r] = -1e30f;
    }
#pragma unroll
    for (int r = 0; r < 4; ++r) {
      float m = acc[tt][0][r];
#pragma unroll
      for (int nt = 1; nt < 12; ++nt) m = fmaxf(m, acc[tt][nt][r]);
#pragma unroll
      for (int off = 1; off < 16; off <<= 1) m = fmaxf(m, __shfl_xor(m, off));
      float s = 0.f;
#pragma unroll
      for (int nt = 0; nt < 12; ++nt) {
        const float e = __expf(acc[tt][nt][r] - m);
        acc[tt][nt][r] = e;
        s += e;
      }
#pragma unroll
      for (int off = 1; off < 16; off <<= 1) s += __shfl_xor(s, off);
      inv_l[tt][r] = 1.0f / s;
    }
    const int mrow0 = (2 * w + tt) * 16 + quad * 4;
#pragma unroll
    for (int r = 0; r < 4; ++r)
#pragma unroll
      for (int nt = 0; nt < 12; ++nt)
        P[(mrow0 + r) * PSTR + nt * 16 + l16] = f2h(acc[tt][nt][r]);
  }
  __syncthreads();

  // ---- PV: o[tt][nd], rows=heads, cols=d (nd*16+l16); 6 K-steps over 192 keys
  f32x4 o[2][4] = {};
#pragma unroll
  for (int kst = 0; kst < 6; ++kst) {
    const f16x8 a0 = *(const f16x8*)(&P[((2 * w + 0) * 16 + l16) * PSTR + kst * 32 + quad * 8]);
    const f16x8 a1 = *(const f16x8*)(&P[((2 * w + 1) * 16 + l16) * PSTR + kst * 32 + quad * 8]);
#pragma unroll
    for (int nd = 0; nd < 4; ++nd) {
      const f16x8 b = *(const f16x8*)(&Vt[(nd * 16 + l16) * PSTR + kst * 32 + quad * 8]);
      o[0][nd] = __builtin_amdgcn_mfma_f32_16x16x32_f16(a0, b, o[0][nd], 0, 0, 0);
      o[1][nd] = __builtin_amdgcn_mfma_f32_16x16x32_f16(a1, b, o[1][nd], 0, 0, 0);
    }
  }

  // ---- epilogue: normalize, write obuf f16
#pragma unroll
  for (int tt = 0; tt < 2; ++tt) {
    const size_t obase = (size_t)(i0 + 2 * w + tt) * DMODEL;
#pragma unroll
    for (int nd = 0; nd < 4; ++nd)
#pragma unroll
      for (int r = 0; r < 4; ++r) {
        const int col = (quad * 4 + r) * DHEAD + nd * 16 + l16;
        obuf[obase + col] = f2h(o[tt][nd][r] * inv_l[tt][r]);
      }
  }
}

// ---------------------------------------------------------------- launch
extern "C" void kernel_launch(void* const* d_in, const int* in_sizes, int n_in,
                              void* d_out, int out_size, void* d_ws, size_t ws_size,
                              hipStream_t stream) {
  const float* x    = (const float*)d_in[0];
  const float* Wqkv = (const float*)d_in[1];
  const float* bqkv = (const float*)d_in[2];
  const float* Wout = (const float*)d_in[3];
  const float* bout = (const float*)d_in[4];
  float* out = (float*)d_out;

  char* w = (char*)d_ws;
  ushort* x16  = (ushort*)(w + 0);          // 4,194,304 B
  ushort* w16  = (ushort*)(w + 4194304);    // 2,359,296 B
  ushort* wo16 = (ushort*)(w + 6553600);    // 2,097,152 B
  ushort* k16  = (ushort*)(w + 8650752);    // 270,336 B  (2112 rows x 64; rows >=2048 stay 0xAA)
  ushort* vT   = (ushort*)(w + 8921088);    // 270,336 B  (64 x 2048 + 8KB slack, stays 0xAA)
  ushort* q16  = (ushort*)(w + 9191424);    // 4,194,304 B
  ushort* obuf = (ushort*)(w + 13385728);   // 4,194,304 B   (total ~17.6 MB)

  convert_kernel<<<4224, 256, 0, stream>>>(
      (const float4*)x, (const float4*)Wqkv, (const float4*)Wout,
      (ushort4*)x16, (ushort4*)w16, (ushort4*)wo16);

  dim3 g1(S_LEN / 128, NQKV / 128);  // 16 x 9
  gemm128<1><<<g1, 256, 0, stream>>>(x16, w16, bqkv, nullptr, k16, vT, q16,
                                     S_LEN, NQKV, DMODEL);

  attn_kernel<<<S_LEN / QT, 256, 0, stream>>>(k16, vT, q16, obuf);

  dim3 g2(S_LEN / 128, DMODEL / 128);  // 16 x 8
  gemm128<0><<<g2, 256, 0, stream>>>(obuf, wo16, bout, out, nullptr, nullptr, nullptr,
                                     S_LEN, DMODEL, DMODEL);
}